// Round 8
// baseline (221.133 us; speedup 1.0000x reference)
//
#include <hip/hip_runtime.h>

// R8 = R7 with T=4 row-tiles per wave-iteration (64 rows).
// R7 (T=2) landed 143 us with MfmaUtil 23%, VALUBusy 55%, no pipe saturated:
// per-iteration costs (93 ds_read_b128, bias reads, loop overhead) paid per
// 32 rows. T=4 amortizes them over 64 rows; registers are safe to spend now
// because all reload sources are LDS (no global remat bait): ~220 live < 256.
//
// ws/LDS layout (bytes), written by nerf_stage, copied whole to LDS:
//   0      : 76 A-frags, 1024 B each (frag f: lane l holds short8 at f*1024+l*16)
//            f 0..7 = L1 (nt; k=0..5 W1, k=6 b1) | 8..39 = L2 (ks*8+nt)
//            | 40..71 = L3 (ks*8+nt) | 72..75 = L4 (ks)
//   77824  : bias2 = b2[0..127]  (f32x4 entry nt*4+q)
//   78336  : bias3 = b3[0..127]
//   78848  : b4 padded: q==0 -> b4[0..3], else 0   (f32x4 entry q)
//   total 78912 B (2 blocks/CU at 160 KB LDS -> 8 waves/CU)

typedef __attribute__((ext_vector_type(8))) short short8;
typedef __attribute__((ext_vector_type(4))) float f32x4;
typedef __attribute__((ext_vector_type(2))) float f32x2;
typedef __attribute__((ext_vector_type(4))) unsigned int u32x4;

#define MFMA(a, b, c) __builtin_amdgcn_mfma_f32_16x16x32_bf16((a), (b), (c), 0, 0, 0)

__device__ __forceinline__ unsigned short bfr(float f) {  // fp32->bf16 RNE
  unsigned u = __builtin_bit_cast(unsigned, f);
  u += 0x7FFFu + ((u >> 16) & 1u);
  return (unsigned short)(u >> 16);
}

__device__ __forceinline__ unsigned pkrelu(float a, float b) {
  a = __builtin_fmaxf(a, 0.f);
  b = __builtin_fmaxf(b, 0.f);
#if __has_builtin(__builtin_amdgcn_cvt_pk_bf16_f32)
  auto h = __builtin_amdgcn_cvt_pk_bf16_f32(a, b);
  return __builtin_bit_cast(unsigned, h);
#else
  return (unsigned)bfr(a) | ((unsigned)bfr(b) << 16);
#endif
}

__device__ __forceinline__ short8 pack4(const f32x4& a0, const f32x4& a1) {
  u32x4 u;
  u.x = pkrelu(a0.x, a0.y);
  u.y = pkrelu(a0.z, a0.w);
  u.z = pkrelu(a1.x, a1.y);
  u.w = pkrelu(a1.z, a1.w);
  return __builtin_bit_cast(short8, u);
}

// consumer B k-slot kp <- producer neuron slot sig_inv(kp)
__device__ __forceinline__ int sig_inv(int kp) {
  return ((kp >> 5) << 5) + (((kp >> 2) & 1) << 4) + (((kp >> 3) & 3) << 2) + (kp & 3);
}

__global__ void nerf_stage(const float* __restrict__ W1, const float* __restrict__ b1,
                           const float* __restrict__ W2, const float* __restrict__ b2,
                           const float* __restrict__ W3, const float* __restrict__ b3,
                           const float* __restrict__ W4, const float* __restrict__ b4,
                           void* __restrict__ ws) {
  unsigned short* wf = (unsigned short*)ws;
  float* wb = (float*)((char*)ws + 77824);
  const int idx = blockIdx.x * 256 + threadIdx.x;
  const int stride = gridDim.x * 256;

  for (int p = idx; p < 76 * 64; p += stride) {
    const int f = p >> 6, l = p & 63, m = l & 15, q = l >> 4;
    unsigned short v[8];
#pragma unroll
    for (int j = 0; j < 8; ++j) {
      float val = 0.f;
      if (f < 8) {  // L1: k<6 = W1 row, k==6 = b1 (B-side supplies 1.0)
        const int k = q * 8 + j;
        if (k < 6) val = W1[(f * 16 + m) * 6 + k];
        else if (k == 6) val = b1[f * 16 + m];
      } else if (f < 72) {  // L2/L3: cols sigma^-1-gathered
        int g = f - 8;
        const float* W = W2;
        if (g >= 32) { g -= 32; W = W3; }
        const int ks = g >> 3, nt = g & 7;
        val = W[(nt * 16 + m) * 128 + sig_inv(ks * 32 + q * 8 + j)];
      } else {  // L4: out rows m<4 only
        const int ks = f - 72;
        if (m < 4) val = W4[m * 128 + sig_inv(ks * 32 + q * 8 + j)];
      }
      v[j] = bfr(val);
    }
#pragma unroll
    for (int j = 0; j < 8; ++j) wf[f * 512 + l * 8 + j] = v[j];
  }

  // 272 floats: b2 copy | b3 copy | b4 padded to 4 quads
  for (int e = idx; e < 272; e += stride) {
    float val;
    if (e < 128) val = b2[e];
    else if (e < 256) val = b3[e - 128];
    else val = ((e & 15) < 4) ? b4[e & 3] : 0.f;
    wb[e] = val;
  }
}

__launch_bounds__(256)
__global__ void nerf_main(const float* __restrict__ x, float* __restrict__ out,
                          const void* __restrict__ ws, int nGroups) {
  __shared__ __align__(16) unsigned short lds[39456];  // 78912 B

  {  // copy the whole constant slab: 78912/16 = 4932 16B chunks
    const u32x4* src = (const u32x4*)ws;
    u32x4* dst = (u32x4*)lds;
    for (int i = threadIdx.x; i < 4932; i += 256) dst[i] = src[i];
  }
  __syncthreads();

  const int lane = threadIdx.x & 63;
  const int wid = threadIdx.x >> 6;
  const int q = lane >> 4;
  const int n = lane & 15;

  const int waveId = blockIdx.x * 4 + wid;
  const int totalWaves = gridDim.x * 4;

  const unsigned short* lw = lds + lane * 8;              // frag f at + f*512
  const f32x4* bias2 = (const f32x4*)((const char*)lds + 77824) + q;  // + nt*4
  const f32x4* bias3 = (const f32x4*)((const char*)lds + 78336) + q;  // + nt*4
  const f32x4* b4p   = (const f32x4*)((const char*)lds + 78848) + q;

  const f32x4 zf = {0.f, 0.f, 0.f, 0.f};

  float px[4][6] = {};
  int g = waveId;
  if (g < nGroups && q == 0) {
#pragma unroll
    for (int t = 0; t < 4; ++t) {
      const float* p = x + (g * 64 + t * 16 + n) * 6;
      f32x2 a = *(const f32x2*)p, b = *(const f32x2*)(p + 2), c = *(const f32x2*)(p + 4);
      px[t][0] = a.x; px[t][1] = a.y; px[t][2] = b.x;
      px[t][3] = b.y; px[t][4] = c.x; px[t][5] = c.y;
    }
  }

  for (; g < nGroups; g += totalWaves) {
    // ---- x -> layer-1 B frags (q==0: k0..5 = x, k6 = 1.0 bias slot) ----
    short8 xb[4];
#pragma unroll
    for (int t = 0; t < 4; ++t) {
      short8 v = {0, 0, 0, 0, 0, 0, 0, 0};
      if (q == 0) {
        v[0] = (short)bfr(px[t][0]); v[1] = (short)bfr(px[t][1]);
        v[2] = (short)bfr(px[t][2]); v[3] = (short)bfr(px[t][3]);
        v[4] = (short)bfr(px[t][4]); v[5] = (short)bfr(px[t][5]);
        v[6] = (short)0x3F80;  // bf16 1.0
      }
      xb[t] = v;
    }
    const int gn = g + totalWaves;
    if (gn < nGroups && q == 0) {
#pragma unroll
      for (int t = 0; t < 4; ++t) {
        const float* p = x + (gn * 64 + t * 16 + n) * 6;
        f32x2 a = *(const f32x2*)p, b = *(const f32x2*)(p + 2), c = *(const f32x2*)(p + 4);
        px[t][0] = a.x; px[t][1] = a.y; px[t][2] = b.x;
        px[t][3] = b.y; px[t][4] = c.x; px[t][5] = c.y;
      }
    }

    short8 B1[4][4], B2[4][4];

    // ---- layer 1 (frags from LDS; bias in k-slot 6; C = 0) ----
#pragma unroll
    for (int ntp = 0; ntp < 4; ++ntp) {
      const short8 w0 = *(const short8*)(lw + (2 * ntp) * 512);
      const short8 w1 = *(const short8*)(lw + (2 * ntp + 1) * 512);
      f32x4 a0[4], a1[4];
#pragma unroll
      for (int t = 0; t < 4; ++t) {
        a0[t] = MFMA(w0, xb[t], zf);
        a1[t] = MFMA(w1, xb[t], zf);
      }
#pragma unroll
      for (int t = 0; t < 4; ++t) B1[t][ntp] = pack4(a0[t], a1[t]);
    }

    // ---- layer 2 (W2 frags 8..39; bias as C at ks==0) ----
#pragma unroll
    for (int ntp = 0; ntp < 4; ++ntp) {
      f32x4 a0[4], a1[4];
#pragma unroll
      for (int ks = 0; ks < 4; ++ks) {
        const short8 w0 = *(const short8*)(lw + (8 + ks * 8 + 2 * ntp) * 512);
        const short8 w1 = *(const short8*)(lw + (8 + ks * 8 + 2 * ntp + 1) * 512);
        if (ks == 0) {
          const f32x4 bv0 = bias2[(2 * ntp) * 4];
          const f32x4 bv1 = bias2[(2 * ntp + 1) * 4];
#pragma unroll
          for (int t = 0; t < 4; ++t) {
            a0[t] = MFMA(w0, B1[t][0], bv0);
            a1[t] = MFMA(w1, B1[t][0], bv1);
          }
        } else {
#pragma unroll
          for (int t = 0; t < 4; ++t) {
            a0[t] = MFMA(w0, B1[t][ks], a0[t]);
            a1[t] = MFMA(w1, B1[t][ks], a1[t]);
          }
        }
      }
#pragma unroll
      for (int t = 0; t < 4; ++t) B2[t][ntp] = pack4(a0[t], a1[t]);
    }

    // ---- layer 3 (W3 frags 40..71) ----
#pragma unroll
    for (int ntp = 0; ntp < 4; ++ntp) {
      f32x4 a0[4], a1[4];
#pragma unroll
      for (int ks = 0; ks < 4; ++ks) {
        const short8 w0 = *(const short8*)(lw + (40 + ks * 8 + 2 * ntp) * 512);
        const short8 w1 = *(const short8*)(lw + (40 + ks * 8 + 2 * ntp + 1) * 512);
        if (ks == 0) {
          const f32x4 bv0 = bias3[(2 * ntp) * 4];
          const f32x4 bv1 = bias3[(2 * ntp + 1) * 4];
#pragma unroll
          for (int t = 0; t < 4; ++t) {
            a0[t] = MFMA(w0, B2[t][0], bv0);
            a1[t] = MFMA(w1, B2[t][0], bv1);
          }
        } else {
#pragma unroll
          for (int t = 0; t < 4; ++t) {
            a0[t] = MFMA(w0, B2[t][ks], a0[t]);
            a1[t] = MFMA(w1, B2[t][ks], a1[t]);
          }
        }
      }
#pragma unroll
      for (int t = 0; t < 4; ++t) B1[t][ntp] = pack4(a0[t], a1[t]);  // reuse B1
    }

    // ---- layer 4 (frags 72..75; out rows at q==0) ----
    f32x4 o[4];
    {
      const f32x4 bv = b4p[0];
#pragma unroll
      for (int ks = 0; ks < 4; ++ks) {
        const short8 w = *(const short8*)(lw + (72 + ks) * 512);
        if (ks == 0) {
#pragma unroll
          for (int t = 0; t < 4; ++t) o[t] = MFMA(w, B1[t][0], bv);
        } else {
#pragma unroll
          for (int t = 0; t < 4; ++t) o[t] = MFMA(w, B1[t][ks], o[t]);
        }
      }
    }
    if (q == 0) {
#pragma unroll
      for (int t = 0; t < 4; ++t)
        *(f32x4*)(out + (g * 64 + t * 16 + n) * 4) = o[t];
    }
  }
}

extern "C" void kernel_launch(void* const* d_in, const int* in_sizes, int n_in,
                              void* d_out, int out_size, void* d_ws, size_t ws_size,
                              hipStream_t stream) {
  const float* x  = (const float*)d_in[0];
  const float* W1 = (const float*)d_in[1];
  const float* b1 = (const float*)d_in[2];
  const float* W2 = (const float*)d_in[3];
  const float* b2 = (const float*)d_in[4];
  const float* W3 = (const float*)d_in[5];
  const float* b3 = (const float*)d_in[6];
  const float* W4 = (const float*)d_in[7];
  const float* b4 = (const float*)d_in[8];
  float* out = (float*)d_out;

  const int N = in_sizes[0] / 6;
  const int nGroups = N / 64;  // 4 tiles of 16 rows per wave-iteration -> 16384

  nerf_stage<<<dim3(4), dim3(256), 0, stream>>>(W1, b1, W2, b2, W3, b3, W4, b4, d_ws);

  // 512 blocks = 2/CU (77 KB LDS each); 2048 waves x exactly 8 iterations
  nerf_main<<<dim3(512), dim3(256), 0, stream>>>(x, out, d_ws, nGroups);
}